// Round 1
// baseline (215.203 us; speedup 1.0000x reference)
//
#include <hip/hip_runtime.h>
#include <hip/hip_bf16.h>

// WindowAttention — single fused kernel per window (qkv + biased attn + proj).
// r5: 1024-thread blocks (16 waves/CU, was 8) + operand-swapped MFMA epilogues
//     so all LDS epilogue stores are packed ds_write_b64 (was scalar b16) and
//     the final global store is float4. LDS 161792 B -> still 1 block/CU.
// Inputs fp32, compute bf16 MFMA, output fp32.
// B=1024 windows, N=64 tokens, H=8 heads, hd=32, DIM=256, P=4.
// Fourier biases folded into QK^T as 16 extra K-dims:
//   Q-side k=32+idx holds raw feats [c_p|s_p|ca_p|sa_p]; K-side holds
//   per-head coefficient-mixed feats; k=48..63 zero; a_r[0],a_p[0] drop in softmax.

using short8  = __attribute__((ext_vector_type(8))) short;
using short4v = __attribute__((ext_vector_type(4))) short;
using floatx4 = __attribute__((ext_vector_type(4))) float;

#define PI_F    3.14159265358979323846f
#define SCALE_F 0.17677669529663687f   // 32^-0.5

__device__ __forceinline__ short bfs(float x) {
  __hip_bfloat16 h = __float2bfloat16(x);
  return __builtin_bit_cast(short, h);
}

// ---------------- kernel 1: weights fp32 -> bf16 into ws ----------------
__global__ void prep_kernel(const float* __restrict__ qw,
                            const float* __restrict__ pw,
                            __hip_bfloat16* __restrict__ dst) {
  int g = blockIdx.x * 256 + threadIdx.x;  // 65536 threads, one float4 each
  const float4* src;
  __hip_bfloat16* d;
  if (g < 49152) { src = (const float4*)qw + g; d = dst + g * 4; }
  else { int g2 = g - 49152; src = (const float4*)pw + g2; d = dst + 196608 + g2 * 4; }
  float4 v = *src;
  d[0] = __float2bfloat16(v.x);
  d[1] = __float2bfloat16(v.y);
  d[2] = __float2bfloat16(v.z);
  d[3] = __float2bfloat16(v.w);
}

__device__ __forceinline__ void fourier_feats(float dv, int col, float* f) {
  float s1, c1; __sincosf(PI_F * dv, &s1, &c1);
  float c2 = c1*c1 - s1*s1, s2 = 2.f*s1*c1;
  float c3 = c2*c1 - s2*s1, s3 = s2*c1 + c2*s1;
  float c4 = c2*c2 - s2*s2, s4 = 2.f*s2*c2;
  float sa1, ca1; __sincosf((2.f * PI_F / 64.f) * (float)col, &sa1, &ca1);
  float ca2 = ca1*ca1 - sa1*sa1, sa2 = 2.f*sa1*ca1;
  float ca3 = ca2*ca1 - sa2*sa1, sa3 = sa2*ca1 + ca2*sa1;
  float ca4 = ca2*ca2 - sa2*sa2, sa4 = 2.f*sa2*ca2;
  f[0]=c1;  f[1]=c2;  f[2]=c3;  f[3]=c4;
  f[4]=s1;  f[5]=s2;  f[6]=s3;  f[7]=s4;
  f[8]=ca1; f[9]=ca2; f[10]=ca3; f[11]=ca4;
  f[12]=sa1; f[13]=sa2; f[14]=sa3; f[15]=sa4;
}

// ---------------- kernel 2: fully fused per-window ----------------
__global__ __launch_bounds__(1024, 4) void fused_kernel(
    const float* __restrict__ x, const float* __restrict__ D,
    const float* __restrict__ a_p, const float* __restrict__ b_p,
    const float* __restrict__ a_r, const float* __restrict__ b_r,
    const __hip_bfloat16* __restrict__ wq, const float* __restrict__ qkv_b,
    const __hip_bfloat16* __restrict__ pwb, const float* __restrict__ pb,
    float* __restrict__ out)
{
  constexpr int LDX = 264, LDQ = 264, LDK = 264, LDQf = 40, LDKm = 136,
                LDVt = 72, LDP = 68, LDO = 264;
  // sScr: phase1 = x tile [64][264] (16896); phase2 = 16 wave-private P stripes
  // [16][68] (17408); phase3 = O [64][264].
  __shared__ __align__(16) __hip_bfloat16 sScr[17408];      // 34816 B
  __shared__ __align__(16) __hip_bfloat16 sQ  [64 * 264];   // 33792 B (scaled q, all heads)
  __shared__ __align__(16) __hip_bfloat16 sK  [64 * 264];   // 33792 B
  __shared__ __align__(16) __hip_bfloat16 sQf [64 * 40];    //  5120 B (feats|zeros)
  __shared__ __align__(16) __hip_bfloat16 sKm [64 * 136];   // 17408 B (mixed feats, 8 heads)
  __shared__ __align__(16) __hip_bfloat16 sVt [256 * 72];   // 36864 B ([dim][token])
  // total 161792 B -> 1 block/CU, 16 waves

  const int tid = threadIdx.x;
  const int lane = tid & 63, w = tid >> 6;          // 16 waves
  const int laneN = lane & 15, laneQ = lane >> 4;
  const int b = blockIdx.x;
  const floatx4 fzero = {0.f, 0.f, 0.f, 0.f};
  const short8 zero8 = {0, 0, 0, 0, 0, 0, 0, 0};

  // ---- phase 0: stage x -> sScr (fp32->bf16, packed 8B stores) ----
  const float4* xg = (const float4*)(x + (size_t)b * 16384);
  #pragma unroll
  for (int it = 0; it < 4; ++it) {
    int g = tid + it * 1024;
    float4 v = xg[g];
    int t = g >> 6, c = (g & 63) * 4;
    short4v pk = { bfs(v.x), bfs(v.y), bfs(v.z), bfs(v.w) };
    *(short4v*)&sScr[t * LDX + c] = pk;
  }
  // Q-side feats -> sQf (packed 16B stores)
  if (tid < 64) {
    float f[16];
    fourier_feats(D[b * 64 + tid], tid & 7, f);
    short8 q0, q1;
    #pragma unroll
    for (int i = 0; i < 8; ++i) { q0[i] = bfs(f[i]); q1[i] = bfs(f[8 + i]); }
    *(short8*)&sQf[tid * LDQf +  0] = q0;
    *(short8*)&sQf[tid * LDQf +  8] = q1;
    *(short8*)&sQf[tid * LDQf + 16] = zero8;
    *(short8*)&sQf[tid * LDQf + 24] = zero8;
  }
  // K-side mixed feats (thread -> (token, head)), packed 16B stores
  if (tid < 512) {
    int t = tid >> 3, hh = tid & 7;
    float f[16];
    fourier_feats(D[b * 64 + t], t & 7, f);
    short8 v0, v1;
    #pragma unroll
    for (int p = 0; p < 4; ++p) {
      float ar = a_r[(p + 1) * 8 + hh], br = b_r[p * 8 + hh];
      float ap = a_p[(p + 1) * 8 + hh], bp = b_p[p * 8 + hh];
      float cr = f[p], sr = f[4 + p], ca = f[8 + p], sa = f[12 + p];
      v0[p]     = bfs((ar * cr + br * sr) * 0.25f);
      v0[4 + p] = bfs((ar * sr - br * cr) * 0.25f);
      v1[p]     = bfs((ap * ca - bp * sa) * 0.25f);
      v1[4 + p] = bfs((ap * sa + bp * ca) * 0.25f);
    }
    *(short8*)&sKm[t * LDKm + hh * 16 + 0] = v0;
    *(short8*)&sKm[t * LDKm + hh * 16 + 8] = v1;
  }
  __syncthreads();   // barrier A

  // ---- phase 1: qkv GEMM. wave w owns Q-cols/K-cols/V-dims [16w,16w+16).
  // Q,K tiles computed operand-SWAPPED (D = [qkvcol][token]) so each lane holds
  // 4 contiguous cols -> packed b64 stores into row-major sQ/sK.
  // V tile unswapped (D = [token][vdim]) -> 4 contiguous tokens -> packed b64
  // stores into sVt[dim][token].
  {
    const __hip_bfloat16* w0 = wq + (size_t)(      w * 16 + laneN) * 256;
    const __hip_bfloat16* w1 = wq + (size_t)(256 + w * 16 + laneN) * 256;
    const __hip_bfloat16* w2 = wq + (size_t)(512 + w * 16 + laneN) * 256;
    floatx4 accQ[4], accK[4], accV[4];
    #pragma unroll
    for (int mt = 0; mt < 4; ++mt) { accQ[mt] = fzero; accK[mt] = fzero; accV[mt] = fzero; }
    #pragma unroll
    for (int kk = 0; kk < 8; ++kk) {
      short8 a4[4];
      #pragma unroll
      for (int mt = 0; mt < 4; ++mt)
        a4[mt] = *(const short8*)&sScr[(mt * 16 + laneN) * LDX + kk * 32 + laneQ * 8];
      short8 b0 = *(const short8*)&w0[kk * 32 + laneQ * 8];
      short8 b1 = *(const short8*)&w1[kk * 32 + laneQ * 8];
      short8 b2 = *(const short8*)&w2[kk * 32 + laneQ * 8];
      #pragma unroll
      for (int mt = 0; mt < 4; ++mt) {
        accQ[mt] = __builtin_amdgcn_mfma_f32_16x16x32_bf16(b0, a4[mt], accQ[mt], 0, 0, 0);
        accK[mt] = __builtin_amdgcn_mfma_f32_16x16x32_bf16(b1, a4[mt], accK[mt], 0, 0, 0);
        accV[mt] = __builtin_amdgcn_mfma_f32_16x16x32_bf16(a4[mt], b2, accV[mt], 0, 0, 0);
      }
    }
    float4 bq4 = *(const float4*)&qkv_b[      w * 16 + laneQ * 4];
    float4 bk4 = *(const float4*)&qkv_b[256 + w * 16 + laneQ * 4];
    float bv   = qkv_b[512 + w * 16 + laneN];
    float bqa[4] = {bq4.x, bq4.y, bq4.z, bq4.w};
    float bka[4] = {bk4.x, bk4.y, bk4.z, bk4.w};
    #pragma unroll
    for (int mt = 0; mt < 4; ++mt) {
      short4v pq, pk, pv;
      #pragma unroll
      for (int r = 0; r < 4; ++r) {
        pq[r] = bfs((accQ[mt][r] + bqa[r]) * SCALE_F);
        pk[r] = bfs(accK[mt][r] + bka[r]);
        pv[r] = bfs(accV[mt][r] + bv);
      }
      *(short4v*)&sQ [(mt * 16 + laneN) * LDQ + w * 16 + laneQ * 4] = pq;
      *(short4v*)&sK [(mt * 16 + laneN) * LDK + w * 16 + laneQ * 4] = pk;
      *(short4v*)&sVt[(w * 16 + laneN) * LDVt + mt * 16 + laneQ * 4] = pv;
    }
  }
  __syncthreads();   // barrier B

  // ---- phase 2: attention. 2 waves/head: h = w>>1, M-tiles gm0..gm0+1 ----
  const int h = w >> 1, gm0 = (w & 1) * 2;
  short8 kf0[4], kf1[4];
  #pragma unroll
  for (int nt = 0; nt < 4; ++nt) {
    kf0[nt] = *(const short8*)&sK[(nt * 16 + laneN) * LDK + h * 32 + laneQ * 8];
    short8 km = *(const short8*)&sKm[(nt * 16 + laneN) * LDKm + h * 16 + (laneQ & 1) * 8];
    kf1[nt] = (laneQ < 2) ? km : zero8;     // k 32..47 mixed, 48..63 zero
  }
  short8 vb[2][2];
  #pragma unroll
  for (int ont = 0; ont < 2; ++ont)
    #pragma unroll
    for (int kk = 0; kk < 2; ++kk)
      vb[ont][kk] = *(const short8*)&sVt[(h * 32 + ont * 16 + laneN) * LDVt + kk * 32 + laneQ * 8];

  floatx4 oacc[2][2];
  __hip_bfloat16* Pw = &sScr[w * 16 * LDP];   // wave-private 16x68 P stripe
  #pragma unroll
  for (int m = 0; m < 2; ++m) {
    const int gm = gm0 + m;
    short8 q0 = *(const short8*)&sQ [(gm * 16 + laneN) * LDQ + h * 32 + laneQ * 8];
    short8 q1 = *(const short8*)&sQf[(gm * 16 + laneN) * LDQf + laneQ * 8];
    floatx4 s[4];
    #pragma unroll
    for (int nt = 0; nt < 4; ++nt) {
      s[nt] = __builtin_amdgcn_mfma_f32_16x16x32_bf16(q0, kf0[nt], fzero, 0, 0, 0);
      s[nt] = __builtin_amdgcn_mfma_f32_16x16x32_bf16(q1, kf1[nt], s[nt], 0, 0, 0);
    }
    #pragma unroll
    for (int r = 0; r < 4; ++r) {
      float mx = fmaxf(fmaxf(s[0][r], s[1][r]), fmaxf(s[2][r], s[3][r]));
      mx = fmaxf(mx, __shfl_xor(mx, 1));
      mx = fmaxf(mx, __shfl_xor(mx, 2));
      mx = fmaxf(mx, __shfl_xor(mx, 4));
      mx = fmaxf(mx, __shfl_xor(mx, 8));
      float e0 = __expf(s[0][r] - mx), e1 = __expf(s[1][r] - mx);
      float e2 = __expf(s[2][r] - mx), e3 = __expf(s[3][r] - mx);
      float sum = e0 + e1 + e2 + e3;
      sum += __shfl_xor(sum, 1);
      sum += __shfl_xor(sum, 2);
      sum += __shfl_xor(sum, 4);
      sum += __shfl_xor(sum, 8);
      float inv = __builtin_amdgcn_rcpf(sum);
      int pr = laneQ * 4 + r;
      Pw[pr * LDP +  0 + laneN] = __float2bfloat16(e0 * inv);
      Pw[pr * LDP + 16 + laneN] = __float2bfloat16(e1 * inv);
      Pw[pr * LDP + 32 + laneN] = __float2bfloat16(e2 * inv);
      Pw[pr * LDP + 48 + laneN] = __float2bfloat16(e3 * inv);
    }
    // wave-internal write->read (compiler inserts lgkmcnt wait); b64 reads (LDP=68)
    short4v p0a = *(const short4v*)&Pw[laneN * LDP + laneQ * 8];
    short4v p0b = *(const short4v*)&Pw[laneN * LDP + laneQ * 8 + 4];
    short4v p1a = *(const short4v*)&Pw[laneN * LDP + 32 + laneQ * 8];
    short4v p1b = *(const short4v*)&Pw[laneN * LDP + 36 + laneQ * 8];
    short8 pf0 = __builtin_shufflevector(p0a, p0b, 0, 1, 2, 3, 4, 5, 6, 7);
    short8 pf1 = __builtin_shufflevector(p1a, p1b, 0, 1, 2, 3, 4, 5, 6, 7);
    // PV operand-swapped: D = [dim][token] -> lane holds 4 contiguous dims
    #pragma unroll
    for (int ont = 0; ont < 2; ++ont) {
      oacc[m][ont] = __builtin_amdgcn_mfma_f32_16x16x32_bf16(vb[ont][0], pf0, fzero, 0, 0, 0);
      oacc[m][ont] = __builtin_amdgcn_mfma_f32_16x16x32_bf16(vb[ont][1], pf1, oacc[m][ont], 0, 0, 0);
    }
  }
  __syncthreads();   // barrier C — all P scratch usage done

  // ---- phase 3: O -> sScr (as [64][264], packed b64), then proj GEMM ----
  #pragma unroll
  for (int m = 0; m < 2; ++m)
    #pragma unroll
    for (int ont = 0; ont < 2; ++ont) {
      short4v pk;
      #pragma unroll
      for (int r = 0; r < 4; ++r) pk[r] = bfs(oacc[m][ont][r]);
      *(short4v*)&sScr[((gm0 + m) * 16 + laneN) * LDO + h * 32 + ont * 16 + laneQ * 4] = pk;
    }
  __syncthreads();   // barrier D

  // proj, operand-swapped: wave w owns 16 output cols; float4 global stores
  const int col0 = w * 16;
  floatx4 pacc[4] = {fzero, fzero, fzero, fzero};
  const __hip_bfloat16* prow = pwb + (size_t)(col0 + laneN) * 256;
  #pragma unroll
  for (int kk = 0; kk < 8; ++kk) {
    short8 pbf = *(const short8*)&prow[kk * 32 + laneQ * 8];
    #pragma unroll
    for (int mt = 0; mt < 4; ++mt) {
      short8 pa = *(const short8*)&sScr[(mt * 16 + laneN) * LDO + kk * 32 + laneQ * 8];
      pacc[mt] = __builtin_amdgcn_mfma_f32_16x16x32_bf16(pbf, pa, pacc[mt], 0, 0, 0);
    }
  }
  float4 bias4 = *(const float4*)&pb[col0 + laneQ * 4];
  float* og = out + (size_t)b * 16384;
  #pragma unroll
  for (int mt = 0; mt < 4; ++mt) {
    float4 o4;
    o4.x = pacc[mt][0] + bias4.x;
    o4.y = pacc[mt][1] + bias4.y;
    o4.z = pacc[mt][2] + bias4.z;
    o4.w = pacc[mt][3] + bias4.w;
    *(float4*)&og[(mt * 16 + laneN) * 256 + col0 + laneQ * 4] = o4;
  }
}

extern "C" void kernel_launch(void* const* d_in, const int* in_sizes, int n_in,
                              void* d_out, int out_size, void* d_ws, size_t ws_size,
                              hipStream_t stream) {
  const float* x      = (const float*)d_in[0];
  const float* D      = (const float*)d_in[1];
  const float* a_p    = (const float*)d_in[2];
  const float* b_p    = (const float*)d_in[3];
  const float* a_r    = (const float*)d_in[4];
  const float* b_r    = (const float*)d_in[5];
  const float* qkv_w  = (const float*)d_in[6];
  const float* qkv_b  = (const float*)d_in[7];
  const float* proj_w = (const float*)d_in[8];
  const float* proj_b = (const float*)d_in[9];

  __hip_bfloat16* wq  = (__hip_bfloat16*)d_ws;   // 196608 bf16 (qkv_w)
  __hip_bfloat16* pwb = wq + 196608;             // 65536 bf16 (proj_w)
  float* out = (float*)d_out;

  prep_kernel<<<256, 256, 0, stream>>>(qkv_w, proj_w, wq);
  fused_kernel<<<1024, 1024, 0, stream>>>(x, D, a_p, b_p, a_r, b_r, wq, qkv_b,
                                          pwb, proj_b, out);
}